// Round 2
// baseline (421.637 us; speedup 1.0000x reference)
//
#include <hip/hip_runtime.h>
#include <hip/hip_cooperative_groups.h>
#include <math.h>

namespace cg = cooperative_groups;

// Shift_11261404250938: per-image shift(trunc(±10%)) + zero-fill, standardize,
// min-max normalize. Standardization cancels in the min-max step, so
// out = (shifted - min) / (max - min).
//
// R3 -> R4: the two-kernel split didn't move dur_us (combined ~120us, same as
// fused 117us). Evidence from the harness fill kernel (6.6 TB/s at 9.6%
// occupancy) says BW comes from per-wave MLP, not occupancy. New structure:
//  - ONE cooperative kernel (grid.sync between min/max and normalize): no
//    second launch, no workspace round-trip (partials in a __device__ array).
//  - 1024 blocks x 256 thr (4 blocks/CU -> guaranteed co-residency).
//  - Phase 1: hand-batched 4-wide independent float4 loads per thread
//    (fill-kernel-style back-to-back dwordx4 issue).
//  - Phase 2: verified R2 gather (two aligned float4 + uniform rotate), with
//    NON-TEMPORAL stores so the 154 MB write stream doesn't evict x from
//    L2/L3 before the re-read (input 154 MB fits in the 256 MB L3).

constexpr int kC = 3, kH = 224, kW = 224;
constexpr int kCHW = kC * kH * kW;   // 150528
constexpr int kROWS = kC * kH;       // 672
constexpr int kQPR  = kW / 4;        // 56 quads per row
constexpr int kNQ   = kROWS * kQPR;  // 37632 quads per image
constexpr int TB    = 256;           // threads per block
constexpr int PARTS = 4;             // blocks per image
constexpr int MAXB  = 256;           // batch size this problem ships

typedef float f32x4 __attribute__((ext_vector_type(4)));

__device__ float2 g_part[MAXB * PARTS];

__device__ __forceinline__ void shifts_for(const float* __restrict__ sfy,
                                           const float* __restrict__ sfx,
                                           int img, int& sy, int& sx)
{
    // Replicate reference fp32 order: ((f*2-1)*0.1f)*size, trunc toward zero.
    float ty = sfy[img] * 2.0f - 1.0f; ty *= 0.1f; ty *= (float)kH;
    sy = (int)truncf(ty);
    float tx = sfx[img] * 2.0f - 1.0f; tx *= 0.1f; tx *= (float)kW;
    sx = (int)truncf(tx);
}

// Misaligned-by-sx gather as two aligned float4 loads + wave-uniform rotate
// (template on sx&3), clamped bases (clamped lanes always masked),
// per-element validity cndmask, aligned non-temporal float4 store.
template <int R>
__device__ __forceinline__ void gather_norm(const float* __restrict__ xb,
                                            float* __restrict__ ob,
                                            int sy, int sx, float mn, float inv,
                                            int f0)
{
    #pragma unroll 2
    for (int f = f0; f < kNQ; f += PARTS * TB) {
        const int rr = f / kQPR;           // row in [0, C*H)
        const int q  = f - rr * kQPR;
        const int j  = rr % kH;            // row within channel
        const int c0 = rr - j;             // c * kH
        const int jj = j + sy;
        const bool rowok = (unsigned)jj < (unsigned)kH;
        const int jc = rowok ? jj : 0;     // clamp (masked anyway)
        const float* __restrict__ src = xb + (c0 + jc) * kW;

        const int i0 = q * 4;
        const int base = i0 + sx - R;      // multiple of 4 (R = sx & 3)
        int qa = base;       qa = qa < 0 ? 0 : qa; qa = qa > kW - 4 ? kW - 4 : qa;
        int qb = base + 4;   qb = qb < 0 ? 0 : qb; qb = qb > kW - 4 ? kW - 4 : qb;
        const float4 av = *(const float4*)(src + qa);
        const float4 bv = *(const float4*)(src + qb);
        const float* a = (const float*)&av;
        const float* b = (const float*)&bv;

        float sel[4];
        #pragma unroll
        for (int k = 0; k < 4; ++k)
            sel[k] = (k + R < 4) ? a[k + R] : b[k + R - 4];

        f32x4 o;
        #pragma unroll
        for (int k = 0; k < 4; ++k) {
            const int s = i0 + k + sx;     // source column
            const float v = (rowok && (unsigned)s < (unsigned)kW) ? sel[k] : 0.0f;
            o[k] = (v - mn) * inv;
        }
        __builtin_nontemporal_store(o, (f32x4*)(ob + rr * kW + i0)); // 16B aligned
    }
}

__global__ __launch_bounds__(TB, 4) void shift_norm_coop(
    const float* __restrict__ x, const float* __restrict__ sfy,
    const float* __restrict__ sfx, float* __restrict__ out)
{
    const int img  = blockIdx.x / PARTS;
    const int part = blockIdx.x - img * PARTS;
    const float* __restrict__ xb = x + (size_t)img * kCHW;
    float* __restrict__ ob = out + (size_t)img * kCHW;
    const int tid = threadIdx.x;

    int sy, sx; shifts_for(sfy, sfx, img, sy, sx);

    // Valid input sub-rectangle (rows/cols of x that survive the shift).
    const int rlo = sy > 0 ? sy : 0;
    const int rhi = kH + (sy < 0 ? sy : 0);
    const int clo = sx > 0 ? sx : 0;
    const int chi = kW + (sx < 0 ? sx : 0);

    float vmin = INFINITY, vmax = -INFINITY;

    // ---------------- Phase 1: batched-MLP streaming min/max ----------------
    // 4 independent float4 loads issued back-to-back, then masked reduce.
    // Invalid (shifted-out) elements -> 0 == the zero-fill's contribution.
    constexpr int STR = PARTS * TB;        // 1024 quads
    int f = part * TB + tid;
    for (; f + 3 * STR < kNQ; f += 4 * STR) {
        float4 v[4];
        int  i0u[4];
        bool roku[4];
        #pragma unroll
        for (int u = 0; u < 4; ++u) {
            const int ff = f + u * STR;
            const int rr = ff / kQPR;
            const int q  = ff - rr * kQPR;
            const int j  = rr % kH;
            roku[u] = (j >= rlo) & (j < rhi);
            i0u[u]  = q * 4;
            v[u] = *(const float4*)(xb + rr * kW + q * 4);
        }
        #pragma unroll
        for (int u = 0; u < 4; ++u) {
            const float* vv = (const float*)&v[u];
            #pragma unroll
            for (int k = 0; k < 4; ++k) {
                const int i = i0u[u] + k;
                const float val = (roku[u] & (i >= clo) & (i < chi)) ? vv[k] : 0.0f;
                vmin = fminf(vmin, val);
                vmax = fmaxf(vmax, val);
            }
        }
    }
    for (; f < kNQ; f += STR) {            // remainder
        const int rr = f / kQPR;
        const int q  = f - rr * kQPR;
        const int j  = rr % kH;
        const bool rok = (j >= rlo) & (j < rhi);
        const float4 v4 = *(const float4*)(xb + rr * kW + q * 4);
        const float* vv = (const float*)&v4;
        #pragma unroll
        for (int k = 0; k < 4; ++k) {
            const int i = q * 4 + k;
            const float val = (rok & (i >= clo) & (i < chi)) ? vv[k] : 0.0f;
            vmin = fminf(vmin, val);
            vmax = fmaxf(vmax, val);
        }
    }

    // Wave (64-lane) shuffle reduction, then cross-wave via LDS.
    #pragma unroll
    for (int off = 32; off > 0; off >>= 1) {
        vmin = fminf(vmin, __shfl_down(vmin, off));
        vmax = fmaxf(vmax, __shfl_down(vmax, off));
    }
    __shared__ float smin[TB / 64], smax[TB / 64];
    const int wave = tid >> 6, lane = tid & 63;
    if (lane == 0) { smin[wave] = vmin; smax[wave] = vmax; }
    __syncthreads();
    if (tid == 0) {
        float mn = smin[0], mx = smax[0];
        #pragma unroll
        for (int w2 = 1; w2 < TB / 64; ++w2) {
            mn = fminf(mn, smin[w2]);
            mx = fmaxf(mx, smax[w2]);
        }
        g_part[blockIdx.x] = make_float2(mn, mx);
    }

    // ---------------- grid-wide barrier ----------------
    cg::this_grid().sync();

    // Fold this image's PARTS partials: vector loads (device-coherent after
    // the sync's acquire), one 32B line, butterfly across groups of PARTS.
    {
        const int p = tid & (PARTS - 1);
        const float2 pv = g_part[img * PARTS + p];
        float mn = pv.x, mx = pv.y;
        #pragma unroll
        for (int off = 1; off < PARTS; off <<= 1) {
            mn = fminf(mn, __shfl_xor(mn, off));
            mx = fmaxf(mx, __shfl_xor(mx, off));
        }
        const float inv = 1.0f / (mx - mn);

        // ---------------- Phase 2: gather + normalize + nt-store ----------------
        const int f0 = part * TB + tid;
        switch (sx & 3) {
            case 0: gather_norm<0>(xb, ob, sy, sx, mn, inv, f0); break;
            case 1: gather_norm<1>(xb, ob, sy, sx, mn, inv, f0); break;
            case 2: gather_norm<2>(xb, ob, sy, sx, mn, inv, f0); break;
            default: gather_norm<3>(xb, ob, sy, sx, mn, inv, f0); break;
        }
    }
}

extern "C" void kernel_launch(void* const* d_in, const int* in_sizes, int n_in,
                              void* d_out, int out_size, void* d_ws, size_t ws_size,
                              hipStream_t stream) {
    const float* x  = (const float*)d_in[0];
    const float* fy = (const float*)d_in[1];
    const float* fx = (const float*)d_in[2];
    float* out = (float*)d_out;
    const int B = in_sizes[1];  // shift_fy has one element per image
    void* args[] = { (void*)&x, (void*)&fy, (void*)&fx, (void*)&out };
    hipLaunchCooperativeKernel((const void*)shift_norm_coop,
                               dim3(B * PARTS), dim3(TB), args, 0, stream);
}

// Round 3
// 295.255 us; speedup vs baseline: 1.4280x; 1.4280x over previous
//
#include <hip/hip_runtime.h>
#include <math.h>

// Shift_11261404250938: per-image shift(trunc(±10%)) + zero-fill, standardize,
// min-max normalize. Standardization cancels in the min-max step, so
// out = (shifted - min) / (max - min).
//
// R4 -> R5: coop+grid.sync+NT-stores regressed 117->228us (reverted). Traffic
// has been at the floor (FETCH~=input, WRITE~=output) in every variant; the
// rate (2.6 TB/s vs the fill kernel's demonstrated 6.6) is limited by
// per-quad address math (~45 VALU/16B: idiv, mod, clamps, dual addrs) and
// load->use serialization. R5 restructures to ROW-WISE waves:
//  - lane q = column-quad q (lanes 56-63 idle, 12.5% waste), wave walks rows
//    stride 32 -> ALL column math (base, clamps qa/qb, col-validity masks)
//    is loop-invariant and hoisted out of the 21-iteration row loop.
//  - row index/validity is wave-uniform (readfirstlane -> SGPR pipe).
//  - masking folded into multiplies: out = fma(sel*cm, rowok?inv:0, -mn*inv).
//    0-contributions stay correct: artificial 0 exists <=> that shift != 0
//    <=> zero-fill exists (invariant verified since R2).
//  - two plain kernels via workspace partials (R3 structure), grid
//    B*8 x 256thr = 8 blocks/CU, 21 independent iters/wave for deep MLP.

constexpr int kC = 3, kH = 224, kW = 224;
constexpr int kCHW  = kC * kH * kW;  // 150528
constexpr int kROWS = kC * kH;       // 672
constexpr int kQPR  = kW / 4;        // 56 quads per row
constexpr int TB    = 256;           // 4 waves per block
constexpr int PARTS = 8;             // blocks per image
constexpr int WVB   = TB / 64;       // 4 waves per block
constexpr int WPI   = PARTS * WVB;   // 32 waves per image
constexpr int RPW   = kROWS / WPI;   // 21 rows per wave (exact)

typedef float f32x4 __attribute__((ext_vector_type(4)));

__device__ __forceinline__ void shifts_for(const float* __restrict__ sfy,
                                           const float* __restrict__ sfx,
                                           int img, int& sy, int& sx)
{
    // Replicate reference fp32 order: ((f*2-1)*0.1f)*size, trunc toward zero.
    float ty = sfy[img] * 2.0f - 1.0f; ty *= 0.1f; ty *= (float)kH;
    sy = (int)truncf(ty);
    float tx = sfx[img] * 2.0f - 1.0f; tx *= 0.1f; tx *= (float)kW;
    sx = (int)truncf(tx);
}

// ---------------- Kernel 1: per-slice min/max partials ----------------
__global__ __launch_bounds__(TB) void minmax_k(
    const float* __restrict__ x, const float* __restrict__ sfy,
    const float* __restrict__ sfx, float2* __restrict__ ws)
{
    const int img  = blockIdx.x / PARTS;
    const int part = blockIdx.x - img * PARTS;
    const float* __restrict__ xb = x + (size_t)img * kCHW;

    int sy, sx; shifts_for(sfy, sfx, img, sy, sx);

    // Valid input sub-rectangle (rows/cols of x that survive the shift).
    const int rlo = sy > 0 ? sy : 0;
    const int rhi = kH + (sy < 0 ? sy : 0);
    const int clo = sx > 0 ? sx : 0;
    const int chi = kW + (sx < 0 ? sx : 0);

    const int tid  = threadIdx.x;
    const int lane = tid & 63;
    // Wave index within the image, forced wave-uniform -> SGPR row math.
    const int wv = __builtin_amdgcn_readfirstlane(tid >> 6) + part * WVB;

    float vmin = INFINITY, vmax = -INFINITY;

    if (lane < kQPR) {
        const int i0 = lane * 4;
        // Loop-invariant per-lane column validity (0/1 multipliers).
        float cm[4];
        #pragma unroll
        for (int k = 0; k < 4; ++k)
            cm[k] = ((i0 + k) >= clo && (i0 + k) < chi) ? 1.0f : 0.0f;

        #pragma unroll 3
        for (int t = 0; t < RPW; ++t) {
            const int rr = wv + t * WPI;           // row in [0, C*H)
            const int j  = rr % kH;                // scalar (SGPR magic-mul)
            const float srm = (j >= rlo && j < rhi) ? 1.0f : 0.0f;
            const f32x4 v = *(const f32x4*)(xb + rr * kW + i0);
            #pragma unroll
            for (int k = 0; k < 4; ++k) {
                const float val = v[k] * cm[k] * srm;  // invalid -> 0 (legal)
                vmin = fminf(vmin, val);
                vmax = fmaxf(vmax, val);
            }
        }
    }
    // Idle lanes (56-63) carry +inf/-inf into the reduction -> no effect.

    #pragma unroll
    for (int off = 32; off > 0; off >>= 1) {
        vmin = fminf(vmin, __shfl_down(vmin, off));
        vmax = fmaxf(vmax, __shfl_down(vmax, off));
    }
    __shared__ float smin[WVB], smax[WVB];
    if (lane == 0) { smin[tid >> 6] = vmin; smax[tid >> 6] = vmax; }
    __syncthreads();
    if (tid == 0) {
        float mn = smin[0], mx = smax[0];
        #pragma unroll
        for (int w = 1; w < WVB; ++w) {
            mn = fminf(mn, smin[w]);
            mx = fmaxf(mx, smax[w]);
        }
        ws[img * PARTS + part] = make_float2(mn, mx);
    }
}

// ---------------- Kernel 2: row-wise gather + normalize + store ----------------
// Misaligned-by-sx gather as two aligned float4 loads + compile-time rotate
// (R = sx & 3; base is always a multiple of 4, so clamped lanes are always
// fully masked -- verified property from R2). Column masks/addresses hoisted.
template <int R>
__device__ __forceinline__ void gather_rows(const float* __restrict__ xb,
                                            float* __restrict__ ob,
                                            int sy, int sx, float inv,
                                            float zoff, int wv, int lane)
{
    if (lane >= kQPR) return;
    const int i0   = lane * 4;
    const int base = i0 + sx - R;                  // multiple of 4
    int qa = base;     qa = qa < 0 ? 0 : qa; qa = qa > kW - 4 ? kW - 4 : qa;
    int qb = base + 4; qb = qb < 0 ? 0 : qb; qb = qb > kW - 4 ? kW - 4 : qb;

    float cm[4];
    #pragma unroll
    for (int k = 0; k < 4; ++k) {
        const int s = i0 + k + sx;                 // source column
        cm[k] = ((unsigned)s < (unsigned)kW) ? 1.0f : 0.0f;
    }

    #pragma unroll 3
    for (int t = 0; t < RPW; ++t) {
        const int rr = wv + t * WPI;               // output row in [0, C*H)
        const int j  = rr % kH;                    // scalar
        const int c0 = rr - j;                     // c * kH
        const int jj = j + sy;
        const bool rowok = (unsigned)jj < (unsigned)kH;
        const int jc = rowok ? jj : 0;             // clamp (masked anyway)
        const float scale = rowok ? inv : 0.0f;
        const float* __restrict__ src = xb + (c0 + jc) * kW;

        const f32x4 av = *(const f32x4*)(src + qa);
        const f32x4 bv = *(const f32x4*)(src + qb);
        float sel[4];
        #pragma unroll
        for (int k = 0; k < 4; ++k)
            sel[k] = (k + R < 4) ? av[k + R] : bv[k + R - 4];

        f32x4 o;
        #pragma unroll
        for (int k = 0; k < 4; ++k)
            o[k] = fmaf(sel[k] * cm[k], scale, zoff);  // invalid -> (0-mn)*inv
        *(f32x4*)(ob + rr * kW + i0) = o;          // 16B aligned
    }
}

__global__ __launch_bounds__(TB) void norm_k(
    const float* __restrict__ x, const float* __restrict__ sfy,
    const float* __restrict__ sfx, const float2* __restrict__ ws,
    float* __restrict__ out)
{
    const int img  = blockIdx.x / PARTS;
    const int part = blockIdx.x - img * PARTS;
    const float* __restrict__ xb = x + (size_t)img * kCHW;
    float* __restrict__ ob = out + (size_t)img * kCHW;

    int sy, sx; shifts_for(sfy, sfx, img, sy, sx);

    // Fold this image's 8 partials (uniform addresses, L2-hit).
    float mn = INFINITY, mx = -INFINITY;
    #pragma unroll
    for (int p = 0; p < PARTS; ++p) {
        const float2 v = ws[img * PARTS + p];
        mn = fminf(mn, v.x);
        mx = fmaxf(mx, v.y);
    }
    const float inv  = 1.0f / (mx - mn);
    const float zoff = (0.0f - mn) * inv;

    const int lane = threadIdx.x & 63;
    const int wv = __builtin_amdgcn_readfirstlane(threadIdx.x >> 6) + part * WVB;

    switch (sx & 3) {
        case 0: gather_rows<0>(xb, ob, sy, sx, inv, zoff, wv, lane); break;
        case 1: gather_rows<1>(xb, ob, sy, sx, inv, zoff, wv, lane); break;
        case 2: gather_rows<2>(xb, ob, sy, sx, inv, zoff, wv, lane); break;
        default: gather_rows<3>(xb, ob, sy, sx, inv, zoff, wv, lane); break;
    }
}

extern "C" void kernel_launch(void* const* d_in, const int* in_sizes, int n_in,
                              void* d_out, int out_size, void* d_ws, size_t ws_size,
                              hipStream_t stream) {
    const float* x  = (const float*)d_in[0];
    const float* fy = (const float*)d_in[1];
    const float* fx = (const float*)d_in[2];
    float* out = (float*)d_out;
    const int B = in_sizes[1];  // shift_fy has one element per image
    float2* ws = (float2*)d_ws; // B * PARTS float2 partials (16 KB @ B=256)
    minmax_k<<<B * PARTS, TB, 0, stream>>>(x, fy, fx, ws);
    norm_k<<<B * PARTS, TB, 0, stream>>>(x, fy, fx, ws, out);
}